// Round 3
// baseline (98.404 us; speedup 1.0000x reference)
//
#include <hip/hip_runtime.h>
#include <math.h>

// Layout: 16 complex amplitudes per lane, 4 batch elements per wave64.
// Physical amp index p (8 bits) = l<<4 | r,  l = lane&15 (4 lane bits),
// r = register index (4 reg bits).  lane = elem*16 + l.
// Wire w <-> bit 7-w.  Bits 7..4 (lane, j=3..0) / bits 3..0 (reg).
//
// CNOT handling:
//  - lane-lane ring CNOTs (0,1),(1,2),(2,3): lazy GF(2) relabel of lane bits
//    only (R[j] parity masks, V[j] xor masks, 4-bit, compile-time).
//  - reg-reg ring CNOTs (4,5),(5,6),(6,7): compile-time register renames (free).
//  - mixed (3,4): per-lane conditional reg-pair swap; (7,0): shuffle on half
//    the regs.  Lane maps verified to return to IDENTITY after 4 cycles, so
//    the QCNN section uses plain single-bit masks.

__device__ __forceinline__ float shx(float v, int m) { return __shfl_xor(v, m, 64); }

struct G1 { float r00, i00, r01, i01, r10, i10, r11, i11; };

// U = RZ(phi)@RY(theta) on a lane bit: A=(uAr, +/-uAip), B=(+/-uBrp, uBi);
// only 2 selects per gate (lane-uniform across all 16 regs).
template <int RL, int VL>
__device__ __forceinline__ void u_lane(float (&ar)[16], float (&ai)[16], int l,
                                       float uAr, float uBi, float uAip,
                                       float uAin, float uBrp, float uBrn) {
  const bool hi = (__popc(l & RL) & 1) != 0;
  const float Ai = hi ? uAip : uAin;
  const float Br = hi ? uBrp : uBrn;
  float pr[16], pi[16];
#pragma unroll
  for (int r = 0; r < 16; ++r) { pr[r] = shx(ar[r], VL); pi[r] = shx(ai[r], VL); }
#pragma unroll
  for (int r = 0; r < 16; ++r) {
    const float nr = uAr * ar[r] - Ai * ai[r] + Br * pr[r] - uBi * pi[r];
    const float ni = uAr * ai[r] + Ai * ar[r] + Br * pi[r] + uBi * pr[r];
    ar[r] = nr; ai[r] = ni;
  }
}

// U on a reg bit: pure FMA, no selects, no shuffles.
template <int TB>
__device__ __forceinline__ void u_reg(float (&ar)[16], float (&ai)[16],
                                      float uAr, float uBi, float uAip,
                                      float uBrp) {
#pragma unroll
  for (int lo = 0; lo < 16; ++lo) {
    if (lo & TB) continue;
    const int hi = lo | TB;
    const float lr = ar[lo], li = ai[lo], hr = ar[hi], hj = ai[hi];
    ar[lo] = uAr * lr + uAip * li - uBrp * hr - uBi * hj;
    ai[lo] = uAr * li - uAip * lr - uBrp * hj + uBi * hr;
    ar[hi] = uBrp * lr - uBi * li + uAr * hr - uAip * hj;
    ai[hi] = uBrp * li + uBi * lr + uAr * hj + uAip * hr;
  }
}

// reg-reg CNOT: compile-time register swap (free after SSA).
template <int CB, int TB>
__device__ __forceinline__ void cnot_rr(float (&ar)[16], float (&ai)[16]) {
#pragma unroll
  for (int r = 0; r < 16; ++r) {
    if ((r & CB) && !(r & TB)) {
      const int s = r | TB;
      float t;
      t = ar[r]; ar[r] = ar[s]; ar[s] = t;
      t = ai[r]; ai[r] = ai[s]; ai[s] = t;
    }
  }
}

// mixed CNOT: control = lane parity(RL), target reg bit TB -> cond. swap.
template <int RL, int TB>
__device__ __forceinline__ void cnot_lr(float (&ar)[16], float (&ai)[16], int l) {
  const bool c = (__popc(l & RL) & 1) != 0;
#pragma unroll
  for (int lo = 0; lo < 16; ++lo) {
    if (lo & TB) continue;
    const int hi = lo | TB;
    float t;
    t = c ? ar[hi] : ar[lo]; ar[hi] = c ? ar[lo] : ar[hi]; ar[lo] = t;
    t = c ? ai[hi] : ai[lo]; ai[hi] = c ? ai[lo] : ai[hi]; ai[lo] = t;
  }
}

// mixed CNOT: control reg bit CB, target lane xor-mask VL -> shuffle half regs.
template <int CB, int VL>
__device__ __forceinline__ void cnot_rl(float (&ar)[16], float (&ai)[16]) {
#pragma unroll
  for (int r = 0; r < 16; ++r) {
    if (r & CB) { ar[r] = shx(ar[r], VL); ai[r] = shx(ai[r], VL); }
  }
}

template <int RL, int VL>
__device__ __forceinline__ void crx_ll(float (&ar)[16], float (&ai)[16], int l,
                                       float co, float si) {
  const bool c = (__popc(l & RL) & 1) != 0;
  const float cc = c ? co : 1.f, ss = c ? si : 0.f;
  float pr[16], pi[16];
#pragma unroll
  for (int r = 0; r < 16; ++r) { pr[r] = shx(ar[r], VL); pi[r] = shx(ai[r], VL); }
#pragma unroll
  for (int r = 0; r < 16; ++r) {
    const float nr = cc * ar[r] + ss * pi[r];
    const float ni = cc * ai[r] - ss * pr[r];
    ar[r] = nr; ai[r] = ni;
  }
}

template <int CB, int TB>
__device__ __forceinline__ void crx_rr(float (&ar)[16], float (&ai)[16],
                                       float co, float si) {
#pragma unroll
  for (int lo = 0; lo < 16; ++lo) {
    if (!(lo & CB) || (lo & TB)) continue;
    const int hi = lo | TB;
    const float lr = ar[lo], li = ai[lo], hr = ar[hi], hj = ai[hi];
    ar[lo] = co * lr + si * hj;  ai[lo] = co * li - si * hr;
    ar[hi] = co * hr + si * li;  ai[hi] = co * hj - si * lr;
  }
}

template <int RL, int TB>
__device__ __forceinline__ void crx_lr(float (&ar)[16], float (&ai)[16], int l,
                                       float co, float si) {
  const bool c = (__popc(l & RL) & 1) != 0;
  const float cc = c ? co : 1.f, ss = c ? si : 0.f;
#pragma unroll
  for (int lo = 0; lo < 16; ++lo) {
    if (lo & TB) continue;
    const int hi = lo | TB;
    const float lr = ar[lo], li = ai[lo], hr = ar[hi], hj = ai[hi];
    ar[lo] = cc * lr + ss * hj;  ai[lo] = cc * li - ss * hr;
    ar[hi] = cc * hr + ss * li;  ai[hi] = cc * hj - ss * lr;
  }
}

template <int RL, int VL>
__device__ __forceinline__ void u3_lane(float (&ar)[16], float (&ai)[16], int l,
                                        const G1& g) {
  const bool hi = (__popc(l & RL) & 1) != 0;
  const float Ar = hi ? g.r11 : g.r00, Ai = hi ? g.i11 : g.i00;
  const float Br = hi ? g.r10 : g.r01, Bi = hi ? g.i10 : g.i01;
  float pr[16], pi[16];
#pragma unroll
  for (int r = 0; r < 16; ++r) { pr[r] = shx(ar[r], VL); pi[r] = shx(ai[r], VL); }
#pragma unroll
  for (int r = 0; r < 16; ++r) {
    const float nr = Ar * ar[r] - Ai * ai[r] + Br * pr[r] - Bi * pi[r];
    const float ni = Ar * ai[r] + Ai * ar[r] + Br * pi[r] + Bi * pr[r];
    ar[r] = nr; ai[r] = ni;
  }
}

template <int TB>
__device__ __forceinline__ void u3_reg(float (&ar)[16], float (&ai)[16],
                                       const G1& g) {
#pragma unroll
  for (int lo = 0; lo < 16; ++lo) {
    if (lo & TB) continue;
    const int hi = lo | TB;
    const float lr = ar[lo], li = ai[lo], hr = ar[hi], hj = ai[hi];
    ar[lo] = g.r00 * lr - g.i00 * li + g.r01 * hr - g.i01 * hj;
    ai[lo] = g.r00 * li + g.i00 * lr + g.r01 * hj + g.i01 * hr;
    ar[hi] = g.r10 * lr - g.i10 * li + g.r11 * hr - g.i11 * hj;
    ai[hi] = g.r10 * li + g.i10 * lr + g.r11 * hj + g.i11 * hr;
  }
}

__device__ __forceinline__ G1 u3_gate(const float* __restrict__ u3p, int k) {
  float st, ct, sp, cp, sl, cl;
  __sincosf(0.5f * u3p[3 * k], &st, &ct);
  __sincosf(u3p[3 * k + 1], &sp, &cp);
  __sincosf(u3p[3 * k + 2], &sl, &cl);
  G1 g;
  g.r00 = ct;        g.i00 = 0.f;
  g.r01 = -cl * st;  g.i01 = -sl * st;
  g.r10 = cp * st;   g.i10 = sp * st;
  g.r11 = (cp * cl - sp * sl) * ct;
  g.i11 = (sp * cl + cp * sl) * ct;
  return g;
}

__global__ __launch_bounds__(256, 2) void qcnn_kernel(
    const float* __restrict__ theta, const float* __restrict__ phi,
    const float* __restrict__ crx, const float* __restrict__ u3p,
    float* __restrict__ out, int nbatch) {
  const int tid = blockIdx.x * blockDim.x + threadIdx.x;
  const int wave = tid >> 6;
  const int lane = threadIdx.x & 63;
  const int l = lane & 15;
  int b = wave * 4 + (lane >> 4);
  if (b >= nbatch) b = nbatch - 1;

  float ar[16], ai[16];
#pragma unroll
  for (int r = 0; r < 16; ++r) { ar[r] = 0.f; ai[r] = 0.f; }
  if (l == 0) ar[0] = 1.f;

  const float th = theta[b], ph = phi[b];
  float sth, cth, sph, cph;
  __sincosf(0.5f * th, &sth, &cth);
  __sincosf(0.5f * ph, &sph, &cph);
  const float uAr = cph * cth, uBi = sph * sth;
  const float uAip = sph * cth, uBrp = cph * sth;
  const float uAin = -uAip, uBrn = -uBrp;

#define ULANE(RL, VL) u_lane<RL, VL>(ar, ai, l, uAr, uBi, uAip, uAin, uBrp, uBrn)
#define UREGS() do { u_reg<8>(ar, ai, uAr, uBi, uAip, uBrp); \
                     u_reg<4>(ar, ai, uAr, uBi, uAip, uBrp); \
                     u_reg<2>(ar, ai, uAr, uBi, uAip, uBrp); \
                     u_reg<1>(ar, ai, uAr, uBi, uAip, uBrp); } while (0)
#define RING(RL43, VL07) do { cnot_lr<RL43, 8>(ar, ai, l); \
                              cnot_rr<8, 4>(ar, ai); cnot_rr<4, 2>(ar, ai); \
                              cnot_rr<2, 1>(ar, ai); \
                              cnot_rl<1, VL07>(ar, ai); } while (0)

  // Lane maps per cycle (R[j],V[j], j=0..3 = bits 4..7), computed offline:
  // c1 U: R=[1,2,4,8]   V=[1,2,4,8];   after: R=[15,14,12,8] V=[1,3,6,12]
  // c2 U: ^^ after c1;                 after: R=[5,10,4,8]   V=[1,2,5,10]
  // c3 U: ^^;                          after: R=[3,6,12,8]   V=[1,3,7,15]
  // c4 U: ^^;                          after: identity.
  // wire w in 0..3 -> j = 3-w: RL=R[j], VL=V[j].
  ULANE(8, 8);  ULANE(4, 4);  ULANE(2, 2);  ULANE(1, 1);  UREGS(); RING(15, 12);
  ULANE(8, 12); ULANE(12, 6); ULANE(14, 3); ULANE(15, 1); UREGS(); RING(5, 10);
  ULANE(8, 10); ULANE(4, 5);  ULANE(10, 2); ULANE(5, 1);  UREGS(); RING(3, 15);
  ULANE(8, 15); ULANE(12, 7); ULANE(6, 3);  ULANE(3, 1);  UREGS(); RING(1, 8);
#undef RING
#undef UREGS
#undef ULANE

  // ---- QCNN section (lane maps = identity) ----
  float co, si;
#define LD(k) __sincosf(0.5f * crx[k], &si, &co)
  LD(0); crx_ll<8, 4>(ar, ai, l, co, si);   // (0,1) bits (7,6)
  LD(1); crx_ll<2, 1>(ar, ai, l, co, si);   // (2,3) bits (5,4)
  LD(2); crx_rr<8, 4>(ar, ai, co, si);      // (4,5) bits (3,2)
  LD(3); crx_rr<2, 1>(ar, ai, co, si);      // (6,7) bits (1,0)
  LD(4); crx_ll<4, 2>(ar, ai, l, co, si);   // (1,2) bits (6,5)
  LD(5); crx_lr<1, 8>(ar, ai, l, co, si);   // (3,4) bits (4,3) mixed
  LD(6); crx_rr<4, 2>(ar, ai, co, si);      // (5,6) bits (2,1)

  { G1 g = u3_gate(u3p, 0); u3_lane<4, 4>(ar, ai, l, g); }  // wire 1, bit 6
  { G1 g = u3_gate(u3p, 1); u3_lane<1, 1>(ar, ai, l, g); }  // wire 3, bit 4
  { G1 g = u3_gate(u3p, 2); u3_reg<4>(ar, ai, g); }         // wire 5, bit 2
  { G1 g = u3_gate(u3p, 3); u3_reg<1>(ar, ai, g); }         // wire 7, bit 0

  LD(7); crx_ll<4, 1>(ar, ai, l, co, si);   // (1,3) bits (6,4)
  LD(8); crx_rr<4, 1>(ar, ai, co, si);      // (5,7) bits (2,0)
  LD(9); crx_lr<1, 4>(ar, ai, l, co, si);   // (3,5) bits (4,2) mixed

  { G1 g = u3_gate(u3p, 4); u3_lane<1, 1>(ar, ai, l, g); }  // wire 3
  { G1 g = u3_gate(u3p, 5); u3_reg<1>(ar, ai, g); }         // wire 7

  LD(10); crx_lr<1, 1>(ar, ai, l, co, si);  // (3,7) bits (4,0) mixed

  { G1 g = u3_gate(u3p, 6); u3_reg<1>(ar, ai, g); }         // wire 7
#undef LD

  // <Z_wire7> : sign = bit0 of reg index; reduce over the element's 16 lanes.
  float v = 0.f;
#pragma unroll
  for (int r = 0; r < 16; ++r) {
    const float t = ar[r] * ar[r] + ai[r] * ai[r];
    v += (r & 1) ? -t : t;
  }
  v += shx(v, 1); v += shx(v, 2); v += shx(v, 4); v += shx(v, 8);
  if (l == 0) out[b] = fmaxf(v, 0.f);
}

extern "C" void kernel_launch(void* const* d_in, const int* in_sizes, int n_in,
                              void* d_out, int out_size, void* d_ws, size_t ws_size,
                              hipStream_t stream) {
  const float* theta = (const float*)d_in[0];
  const float* phi = (const float*)d_in[1];
  const float* crx = (const float*)d_in[2];
  const float* u3p = (const float*)d_in[3];
  float* out = (float*)d_out;
  const int nb = in_sizes[0];
  const int elems_per_block = 16;  // 4 waves * 4 elements
  dim3 block(256);
  dim3 grid((nb + elems_per_block - 1) / elems_per_block);
  qcnn_kernel<<<grid, block, 0, stream>>>(theta, phi, crx, u3p, out, nb);
}

// Round 4
// 95.278 us; speedup vs baseline: 1.0328x; 1.0328x over previous
//
#include <hip/hip_runtime.h>
#include <math.h>

// Layout: 8 complex amps/lane, 2 batch elements per wave64 (one per 32-lane
// half).  Physical amp index p (8 bits) = l<<3 | r, l = lane&31 (5 lane
// bits j4..j0), r = reg index (3 bits).  Wire w <-> bit 7-w:
//   wires 0..4 -> lane bits j4..j0 ; wires 5,6,7 -> reg bits 4,2,1 (masks).
//
// Ring CNOTs per cycle: (0,1),(1,2),(2,3),(3,4) lane-lane -> lazy GF(2)
// relabel of the 5 lane bits (compile-time R parity-masks / V xor-masks);
// (4,5) lane->reg: cndmask pair swap; (5,6),(6,7) reg-reg: free renames;
// (7,0) reg->lane: shuffle on regs with bit0.
//
// Lazy map evolution (R[t]^=R[c]; V[c]^=V[t] per lane-lane CNOT), computed
// offline.  U-gate masks (R,V) per cycle for wires 0..4:
//  C1: (16,16)(8,8)(4,4)(2,2)(1,1)      lr-ctrl 31  rl-V 24
//  C2: (16,24)(24,12)(28,6)(30,3)(31,1) lr-ctrl 21  rl-V 20
//  C3: (16,20)(8,10)(20,5)(10,2)(21,1)  lr-ctrl 19  rl-V 30
//  C4: (16,30)(24,15)(12,7)(6,3)(19,1)  lr-ctrl 17  rl-V 17
//  QCNN (final): w0(16,17) w1(8,8) w2(4,4) w3(2,2) w4(17,1)
// Invariants verified: popc(R&V) odd per gate; popc(Rc&Vt) even per CRX.
//
// Shuffles with xor-mask in {1,2,3,7,8,15} use DPP (VALU pipe, ~free)
// instead of ds_swizzle: quad_perm for 1/2/3, row_half_mirror=7,
// row_ror:8=8, row_mirror=15.  All others are single ds_swizzle (mask<32).

template <int M>
__device__ __forceinline__ float shxm(float v) {
  if constexpr (M == 1 || M == 2 || M == 3 || M == 7 || M == 8 || M == 15) {
    constexpr int ctrl = (M == 1) ? 0xB1 : (M == 2) ? 0x4E : (M == 3) ? 0x1B
                         : (M == 7) ? 0x141 : (M == 8) ? 0x128 : 0x140;
    return __int_as_float(__builtin_amdgcn_update_dpp(
        0, __float_as_int(v), ctrl, 0xF, 0xF, true));
  } else {
    return __shfl_xor(v, M, 64);
  }
}

struct G1 { float r00, i00, r01, i01, r10, i10, r11, i11; };

// U = RZ(phi)@RY(theta) on a lane bit; 2 selects/gate, lane-uniform.
template <int RL, int VL>
__device__ __forceinline__ void u_lane(float (&ar)[8], float (&ai)[8], int l,
                                       float uAr, float uBi, float uAip,
                                       float uAin, float uBrp, float uBrn) {
  const bool hi = (__popc(l & RL) & 1) != 0;
  const float Ai = hi ? uAip : uAin;
  const float Br = hi ? uBrp : uBrn;
  float pr[8], pi[8];
#pragma unroll
  for (int r = 0; r < 8; ++r) { pr[r] = shxm<VL>(ar[r]); pi[r] = shxm<VL>(ai[r]); }
#pragma unroll
  for (int r = 0; r < 8; ++r) {
    const float nr = uAr * ar[r] - Ai * ai[r] + Br * pr[r] - uBi * pi[r];
    const float ni = uAr * ai[r] + Ai * ar[r] + Br * pi[r] + uBi * pr[r];
    ar[r] = nr; ai[r] = ni;
  }
}

// U on a reg bit: pure FMA, no selects, no shuffles.
template <int TB>
__device__ __forceinline__ void u_reg(float (&ar)[8], float (&ai)[8],
                                      float uAr, float uBi, float uAip,
                                      float uBrp) {
#pragma unroll
  for (int lo = 0; lo < 8; ++lo) {
    if (lo & TB) continue;
    const int hi = lo | TB;
    const float lr = ar[lo], li = ai[lo], hr = ar[hi], hj = ai[hi];
    ar[lo] = uAr * lr + uAip * li - uBrp * hr - uBi * hj;
    ai[lo] = uAr * li - uAip * lr - uBrp * hj + uBi * hr;
    ar[hi] = uBrp * lr - uBi * li + uAr * hr - uAip * hj;
    ai[hi] = uBrp * li + uBi * lr + uAr * hj + uAip * hr;
  }
}

template <int CB, int TB>
__device__ __forceinline__ void cnot_rr(float (&ar)[8], float (&ai)[8]) {
#pragma unroll
  for (int r = 0; r < 8; ++r) {
    if ((r & CB) && !(r & TB)) {
      const int s = r | TB;
      float t;
      t = ar[r]; ar[r] = ar[s]; ar[s] = t;
      t = ai[r]; ai[r] = ai[s]; ai[s] = t;
    }
  }
}

// control = lane parity(RL), target reg bit TB -> conditional pair swap.
template <int RL, int TB>
__device__ __forceinline__ void cnot_lr(float (&ar)[8], float (&ai)[8], int l) {
  const bool c = (__popc(l & RL) & 1) != 0;
#pragma unroll
  for (int lo = 0; lo < 8; ++lo) {
    if (lo & TB) continue;
    const int hi = lo | TB;
    float t;
    t = c ? ar[hi] : ar[lo]; ar[hi] = c ? ar[lo] : ar[hi]; ar[lo] = t;
    t = c ? ai[hi] : ai[lo]; ai[hi] = c ? ai[lo] : ai[hi]; ai[lo] = t;
  }
}

// control reg bit CB, target lane xor-mask VL -> shuffle half the regs.
template <int CB, int VL>
__device__ __forceinline__ void cnot_rl(float (&ar)[8], float (&ai)[8]) {
#pragma unroll
  for (int r = 0; r < 8; ++r) {
    if (r & CB) { ar[r] = shxm<VL>(ar[r]); ai[r] = shxm<VL>(ai[r]); }
  }
}

template <int RL, int VL>
__device__ __forceinline__ void crx_ll(float (&ar)[8], float (&ai)[8], int l,
                                       float co, float si) {
  const bool c = (__popc(l & RL) & 1) != 0;
  const float cc = c ? co : 1.f, ss = c ? si : 0.f;
  float pr[8], pi[8];
#pragma unroll
  for (int r = 0; r < 8; ++r) { pr[r] = shxm<VL>(ar[r]); pi[r] = shxm<VL>(ai[r]); }
#pragma unroll
  for (int r = 0; r < 8; ++r) {
    const float nr = cc * ar[r] + ss * pi[r];
    const float ni = cc * ai[r] - ss * pr[r];
    ar[r] = nr; ai[r] = ni;
  }
}

template <int CB, int TB>
__device__ __forceinline__ void crx_rr(float (&ar)[8], float (&ai)[8],
                                       float co, float si) {
#pragma unroll
  for (int lo = 0; lo < 8; ++lo) {
    if (!(lo & CB) || (lo & TB)) continue;
    const int hi = lo | TB;
    const float lr = ar[lo], li = ai[lo], hr = ar[hi], hj = ai[hi];
    ar[lo] = co * lr + si * hj;  ai[lo] = co * li - si * hr;
    ar[hi] = co * hr + si * li;  ai[hi] = co * hj - si * lr;
  }
}

template <int RL, int TB>
__device__ __forceinline__ void crx_lr(float (&ar)[8], float (&ai)[8], int l,
                                       float co, float si) {
  const bool c = (__popc(l & RL) & 1) != 0;
  const float cc = c ? co : 1.f, ss = c ? si : 0.f;
#pragma unroll
  for (int lo = 0; lo < 8; ++lo) {
    if (lo & TB) continue;
    const int hi = lo | TB;
    const float lr = ar[lo], li = ai[lo], hr = ar[hi], hj = ai[hi];
    ar[lo] = cc * lr + ss * hj;  ai[lo] = cc * li - ss * hr;
    ar[hi] = cc * hr + ss * li;  ai[hi] = cc * hj - ss * lr;
  }
}

template <int RL, int VL>
__device__ __forceinline__ void u3_lane(float (&ar)[8], float (&ai)[8], int l,
                                        const G1& g) {
  const bool hi = (__popc(l & RL) & 1) != 0;
  const float Ar = hi ? g.r11 : g.r00, Ai = hi ? g.i11 : g.i00;
  const float Br = hi ? g.r10 : g.r01, Bi = hi ? g.i10 : g.i01;
  float pr[8], pi[8];
#pragma unroll
  for (int r = 0; r < 8; ++r) { pr[r] = shxm<VL>(ar[r]); pi[r] = shxm<VL>(ai[r]); }
#pragma unroll
  for (int r = 0; r < 8; ++r) {
    const float nr = Ar * ar[r] - Ai * ai[r] + Br * pr[r] - Bi * pi[r];
    const float ni = Ar * ai[r] + Ai * ar[r] + Br * pi[r] + Bi * pr[r];
    ar[r] = nr; ai[r] = ni;
  }
}

template <int TB>
__device__ __forceinline__ void u3_reg(float (&ar)[8], float (&ai)[8],
                                       const G1& g) {
#pragma unroll
  for (int lo = 0; lo < 8; ++lo) {
    if (lo & TB) continue;
    const int hi = lo | TB;
    const float lr = ar[lo], li = ai[lo], hr = ar[hi], hj = ai[hi];
    ar[lo] = g.r00 * lr - g.i00 * li + g.r01 * hr - g.i01 * hj;
    ai[lo] = g.r00 * li + g.i00 * lr + g.r01 * hj + g.i01 * hr;
    ar[hi] = g.r10 * lr - g.i10 * li + g.r11 * hr - g.i11 * hj;
    ai[hi] = g.r10 * li + g.i10 * lr + g.r11 * hj + g.i11 * hr;
  }
}

__device__ __forceinline__ G1 u3_gate(const float* __restrict__ u3p, int k) {
  float st, ct, sp, cp, sl, cl;
  __sincosf(0.5f * u3p[3 * k], &st, &ct);
  __sincosf(u3p[3 * k + 1], &sp, &cp);
  __sincosf(u3p[3 * k + 2], &sl, &cl);
  G1 g;
  g.r00 = ct;        g.i00 = 0.f;
  g.r01 = -cl * st;  g.i01 = -sl * st;
  g.r10 = cp * st;   g.i10 = sp * st;
  g.r11 = (cp * cl - sp * sl) * ct;
  g.i11 = (sp * cl + cp * sl) * ct;
  return g;
}

__global__ __launch_bounds__(256, 4) void qcnn_kernel(
    const float* __restrict__ theta, const float* __restrict__ phi,
    const float* __restrict__ crx, const float* __restrict__ u3p,
    float* __restrict__ out, int nbatch) {
  const int tid = blockIdx.x * blockDim.x + threadIdx.x;
  const int wave = tid >> 6;
  const int lane = threadIdx.x & 63;
  const int l = lane & 31;
  int b = wave * 2 + (lane >> 5);
  if (b >= nbatch) b = nbatch - 1;

  float ar[8], ai[8];
#pragma unroll
  for (int r = 0; r < 8; ++r) { ar[r] = 0.f; ai[r] = 0.f; }
  if (l == 0) ar[0] = 1.f;

  const float th = theta[b], ph = phi[b];
  float sth, cth, sph, cph;
  __sincosf(0.5f * th, &sth, &cth);
  __sincosf(0.5f * ph, &sph, &cph);
  const float uAr = cph * cth, uBi = sph * sth;
  const float uAip = sph * cth, uBrp = cph * sth;
  const float uAin = -uAip, uBrn = -uBrp;

#define ULANE(RL, VL) u_lane<RL, VL>(ar, ai, l, uAr, uBi, uAip, uAin, uBrp, uBrn)
#define UREGS() do { u_reg<4>(ar, ai, uAr, uBi, uAip, uBrp); \
                     u_reg<2>(ar, ai, uAr, uBi, uAip, uBrp); \
                     u_reg<1>(ar, ai, uAr, uBi, uAip, uBrp); } while (0)
#define RING(RL45, VL70) do { cnot_lr<RL45, 4>(ar, ai, l); \
                              cnot_rr<4, 2>(ar, ai); cnot_rr<2, 1>(ar, ai); \
                              cnot_rl<1, VL70>(ar, ai); } while (0)

  // cycle 1
  ULANE(16, 16); ULANE(8, 8);   ULANE(4, 4);   ULANE(2, 2);  ULANE(1, 1);
  UREGS(); RING(31, 24);
  // cycle 2
  ULANE(16, 24); ULANE(24, 12); ULANE(28, 6);  ULANE(30, 3); ULANE(31, 1);
  UREGS(); RING(21, 20);
  // cycle 3
  ULANE(16, 20); ULANE(8, 10);  ULANE(20, 5);  ULANE(10, 2); ULANE(21, 1);
  UREGS(); RING(19, 30);
  // cycle 4
  ULANE(16, 30); ULANE(24, 15); ULANE(12, 7);  ULANE(6, 3);  ULANE(19, 1);
  UREGS(); RING(17, 17);
#undef RING
#undef UREGS
#undef ULANE

  // ---- QCNN section (final lane maps: w0(16,17) w1(8,8) w2(4,4) w3(2,2)
  // w4(17,1); reg wires 5,6,7 -> bits 4,2,1) ----
  float co, si;
#define LD(k) __sincosf(0.5f * crx[k], &si, &co)
  LD(0); crx_ll<16, 8>(ar, ai, l, co, si);   // (0,1)
  LD(1); crx_ll<4, 2>(ar, ai, l, co, si);    // (2,3)
  LD(2); crx_lr<17, 4>(ar, ai, l, co, si);   // (4,5) mixed
  LD(3); crx_rr<2, 1>(ar, ai, co, si);       // (6,7)
  LD(4); crx_ll<8, 4>(ar, ai, l, co, si);    // (1,2)
  LD(5); crx_ll<2, 1>(ar, ai, l, co, si);    // (3,4)
  LD(6); crx_rr<4, 2>(ar, ai, co, si);       // (5,6)

  { G1 g = u3_gate(u3p, 0); u3_lane<8, 8>(ar, ai, l, g); }  // wire 1
  { G1 g = u3_gate(u3p, 1); u3_lane<2, 2>(ar, ai, l, g); }  // wire 3
  { G1 g = u3_gate(u3p, 2); u3_reg<4>(ar, ai, g); }         // wire 5
  { G1 g = u3_gate(u3p, 3); u3_reg<1>(ar, ai, g); }         // wire 7

  LD(7); crx_ll<8, 2>(ar, ai, l, co, si);    // (1,3)
  LD(8); crx_rr<4, 1>(ar, ai, co, si);       // (5,7)
  LD(9); crx_lr<2, 4>(ar, ai, l, co, si);    // (3,5) mixed

  { G1 g = u3_gate(u3p, 4); u3_lane<2, 2>(ar, ai, l, g); }  // wire 3
  { G1 g = u3_gate(u3p, 5); u3_reg<1>(ar, ai, g); }         // wire 7

  LD(10); crx_lr<2, 1>(ar, ai, l, co, si);   // (3,7) mixed

  { G1 g = u3_gate(u3p, 6); u3_reg<1>(ar, ai, g); }         // wire 7
#undef LD

  // <Z_wire7>: sign = reg bit0; reduce over the element's 32 lanes.
  float v = 0.f;
#pragma unroll
  for (int r = 0; r < 8; ++r) {
    const float t = ar[r] * ar[r] + ai[r] * ai[r];
    v += (r & 1) ? -t : t;
  }
  v += shxm<1>(v); v += shxm<2>(v); v += shxm<4>(v);
  v += shxm<8>(v); v += shxm<16>(v);
  if (l == 0) out[b] = fmaxf(v, 0.f);
}

extern "C" void kernel_launch(void* const* d_in, const int* in_sizes, int n_in,
                              void* d_out, int out_size, void* d_ws, size_t ws_size,
                              hipStream_t stream) {
  const float* theta = (const float*)d_in[0];
  const float* phi = (const float*)d_in[1];
  const float* crx = (const float*)d_in[2];
  const float* u3p = (const float*)d_in[3];
  float* out = (float*)d_out;
  const int nb = in_sizes[0];
  const int elems_per_block = 8;  // 4 waves * 2 elements
  dim3 block(256);
  dim3 grid((nb + elems_per_block - 1) / elems_per_block);
  qcnn_kernel<<<grid, block, 0, stream>>>(theta, phi, crx, u3p, out, nb);
}

// Round 5
// 79.255 us; speedup vs baseline: 1.2416x; 1.2022x over previous
//
#include <hip/hip_runtime.h>
#include <math.h>

// Layout: 8 complex amps/lane, 2 batch elements/wave64 (one per 32-lane half).
// Amp index p = l<<3 | r, l = lane&31 (5 lane bits), r = reg (3 bits).
// NEW: regs packed as float2 along reg bit2 (wire 5):
//   CR[q] = (re[r=q], re[r=q|4]),  CI[q] likewise,  q = r&3 (bits 1,0 = wires 6,7).
// All gates NOT targeting bit2 have pack-uniform coefficients -> v_pk_fma_f32
// (VOP3P) halves FMA issue slots.  Gates with CONTROL on bit2 use per-half
// coefficient vectors (1,co)/(0,si) -> also fully packed.  Only bit2-target
// gates (u_reg4/u3_reg4/crx_lr4: 7 total) stay scalar.
//
// Lane-bit lazy GF(2) CNOT relabeling identical to round 4 (validated):
//  C1 U:(16,16)(8,8)(4,4)(2,2)(1,1)      lr-ctrl 31  rl-V 24
//  C2 U:(16,24)(24,12)(28,6)(30,3)(31,1) lr-ctrl 21  rl-V 20
//  C3 U:(16,20)(8,10)(20,5)(10,2)(21,1)  lr-ctrl 19  rl-V 30
//  C4 U:(16,30)(24,15)(12,7)(6,3)(19,1)  lr-ctrl 17  rl-V 17
//  QCNN: w0(16,17) w1(8,8) w2(4,4) w3(2,2) w4(17,1); reg wires 5,6,7=bits 2,1,0.

typedef float v2f __attribute__((ext_vector_type(2)));

__device__ __forceinline__ v2f pkmul(v2f a, v2f b) {
  v2f d; asm("v_pk_mul_f32 %0, %1, %2" : "=v"(d) : "v"(a), "v"(b)); return d;
}
__device__ __forceinline__ v2f pkfma(v2f a, v2f b, v2f c) {
  v2f d; asm("v_pk_fma_f32 %0, %1, %2, %3" : "=v"(d) : "v"(a), "v"(b), "v"(c)); return d;
}
__device__ __forceinline__ v2f dup(float x) { return (v2f){x, x}; }

template <int M>
__device__ __forceinline__ float shxm(float v) {
  if constexpr (M == 1 || M == 2 || M == 3 || M == 7 || M == 8 || M == 15) {
    constexpr int ctrl = (M == 1) ? 0xB1 : (M == 2) ? 0x4E : (M == 3) ? 0x1B
                         : (M == 7) ? 0x141 : (M == 8) ? 0x128 : 0x140;
    return __int_as_float(__builtin_amdgcn_update_dpp(
        0, __float_as_int(v), ctrl, 0xF, 0xF, true));
  } else {
    return __shfl_xor(v, M, 64);
  }
}
template <int M>
__device__ __forceinline__ v2f shf2(v2f a) {
  return (v2f){shxm<M>(a.x), shxm<M>(a.y)};
}

struct G1 { float r00, i00, r01, i01, r10, i10, r11, i11; };

// Packed complex FMA: R' = Ar*R - Ai*I + Br*PR - Bi*PI ; I' = Ar*I + Ai*R + Br*PI + Bi*PR
__device__ __forceinline__ void cplx_fma(v2f& R, v2f& I, v2f PR, v2f PI,
                                         v2f cAr, v2f cAi, v2f cAiN,
                                         v2f cBr, v2f cBi, v2f cBiN) {
  v2f NR = pkfma(cBiN, PI, pkfma(cBr, PR, pkfma(cAiN, I, pkmul(cAr, R))));
  v2f NI = pkfma(cBi, PR, pkfma(cBr, PI, pkfma(cAi, R, pkmul(cAr, I))));
  R = NR; I = NI;
}

// Packed general 2x2 complex gate on a reg pair (lo,hi), coefficients scalar.
__device__ __forceinline__ void apply_pair(v2f& LR, v2f& LI, v2f& HR, v2f& HI,
                                           float g00r, float g00i, float g01r,
                                           float g01i, float g10r, float g10i,
                                           float g11r, float g11i) {
  const v2f a00r = dup(g00r), a00i = dup(g00i), n00i = dup(-g00i);
  const v2f a01r = dup(g01r), a01i = dup(g01i), n01i = dup(-g01i);
  const v2f a10r = dup(g10r), a10i = dup(g10i), n10i = dup(-g10i);
  const v2f a11r = dup(g11r), a11i = dup(g11i), n11i = dup(-g11i);
  v2f NLR = pkfma(n01i, HI, pkfma(a01r, HR, pkfma(n00i, LI, pkmul(a00r, LR))));
  v2f NLI = pkfma(a01i, HR, pkfma(a01r, HI, pkfma(a00i, LR, pkmul(a00r, LI))));
  v2f NHR = pkfma(n11i, HI, pkfma(a11r, HR, pkfma(n10i, LI, pkmul(a10r, LR))));
  v2f NHI = pkfma(a11i, HR, pkfma(a11r, HI, pkfma(a10i, LR, pkmul(a10r, LI))));
  LR = NLR; LI = NLI; HR = NHR; HI = NHI;
}

// Packed CRX pair mix with coefficient vectors (supports per-half (1,co)/(0,si)).
__device__ __forceinline__ void crx_pairv(v2f& LR, v2f& LI, v2f& HR, v2f& HI,
                                          v2f cCC, v2f cSS, v2f cSSN) {
  v2f NLR = pkfma(cSS, HI, pkmul(cCC, LR));
  v2f NLI = pkfma(cSSN, HR, pkmul(cCC, LI));
  v2f NHR = pkfma(cSS, LI, pkmul(cCC, HR));
  v2f NHI = pkfma(cSSN, LR, pkmul(cCC, HI));
  LR = NLR; LI = NLI; HR = NHR; HI = NHI;
}

// U = RZ@RY on a lane bit (fully packed).
template <int RL, int VL>
__device__ __forceinline__ void u_lane(v2f (&CR)[4], v2f (&CI)[4], int l,
                                       float uAr, float uBi, float uAip,
                                       float uBrp) {
  const bool hi = (__popc(l & RL) & 1) != 0;
  const float Ai = hi ? uAip : -uAip;
  const float Br = hi ? uBrp : -uBrp;
  const v2f cAr = dup(uAr), cAi = dup(Ai), cAiN = dup(-Ai);
  const v2f cBr = dup(Br), cBi = dup(uBi), cBiN = dup(-uBi);
  v2f PR[4], PI[4];
#pragma unroll
  for (int q = 0; q < 4; ++q) { PR[q] = shf2<VL>(CR[q]); PI[q] = shf2<VL>(CI[q]); }
#pragma unroll
  for (int q = 0; q < 4; ++q)
    cplx_fma(CR[q], CI[q], PR[q], PI[q], cAr, cAi, cAiN, cBr, cBi, cBiN);
}

// U on reg bit2 (pack axis) -- scalar within-pair.
__device__ __forceinline__ void u_reg4(v2f (&CR)[4], v2f (&CI)[4], float uAr,
                                       float uBi, float uAip, float uBrp) {
#pragma unroll
  for (int q = 0; q < 4; ++q) {
    const float lr = CR[q].x, li = CI[q].x, hr = CR[q].y, hj = CI[q].y;
    CR[q] = (v2f){uAr * lr + uAip * li - uBrp * hr - uBi * hj,
                  uBrp * lr - uBi * li + uAr * hr - uAip * hj};
    CI[q] = (v2f){uAr * li - uAip * lr - uBrp * hj + uBi * hr,
                  uBrp * li + uBi * lr + uAr * hj + uAip * hr};
  }
}

// ring CNOT (4,5): lane ctrl -> conditional .x/.y swap.
template <int RL>
__device__ __forceinline__ void cnot_lr4(v2f (&CR)[4], v2f (&CI)[4], int l) {
  const bool c = (__popc(l & RL) & 1) != 0;
#pragma unroll
  for (int q = 0; q < 4; ++q) {
    const float ax = CR[q].x, ay = CR[q].y;
    CR[q] = (v2f){c ? ay : ax, c ? ax : ay};
    const float bx = CI[q].x, by = CI[q].y;
    CI[q] = (v2f){c ? by : bx, c ? bx : by};
  }
}

// ring CNOT (5,6): swap .y halves of (0,2),(1,3).
__device__ __forceinline__ void cnot_swap42(v2f (&CR)[4], v2f (&CI)[4]) {
  float t;
  t = CR[0].y; CR[0].y = CR[2].y; CR[2].y = t;
  t = CR[1].y; CR[1].y = CR[3].y; CR[3].y = t;
  t = CI[0].y; CI[0].y = CI[2].y; CI[2].y = t;
  t = CI[1].y; CI[1].y = CI[3].y; CI[3].y = t;
}

// ring CNOT (6,7): full swap CR[2]<->CR[3] (free rename).
__device__ __forceinline__ void cnot_swap21(v2f (&CR)[4], v2f (&CI)[4]) {
  v2f t;
  t = CR[2]; CR[2] = CR[3]; CR[3] = t;
  t = CI[2]; CI[2] = CI[3]; CI[3] = t;
}

// ring CNOT (7,0): reg bit0 ctrl -> shuffle CR[1],CR[3] (both halves).
template <int VL>
__device__ __forceinline__ void cnot_rl(v2f (&CR)[4], v2f (&CI)[4]) {
  CR[1] = shf2<VL>(CR[1]); CI[1] = shf2<VL>(CI[1]);
  CR[3] = shf2<VL>(CR[3]); CI[3] = shf2<VL>(CI[3]);
}

// CRX lane-lane (packed).
template <int RL, int VL>
__device__ __forceinline__ void crx_ll(v2f (&CR)[4], v2f (&CI)[4], int l,
                                       float co, float si) {
  const bool c = (__popc(l & RL) & 1) != 0;
  const float cc = c ? co : 1.f, ss = c ? si : 0.f;
  const v2f cCC = dup(cc), cSS = dup(ss), cSSN = dup(-ss);
  v2f PR[4], PI[4];
#pragma unroll
  for (int q = 0; q < 4; ++q) { PR[q] = shf2<VL>(CR[q]); PI[q] = shf2<VL>(CI[q]); }
#pragma unroll
  for (int q = 0; q < 4; ++q) {
    CR[q] = pkfma(cSS, PI[q], pkmul(cCC, CR[q]));
    CI[q] = pkfma(cSSN, PR[q], pkmul(cCC, CI[q]));
  }
}

// CRX lane ctrl -> target pack axis (scalar within-pair).
template <int RL>
__device__ __forceinline__ void crx_lr4(v2f (&CR)[4], v2f (&CI)[4], int l,
                                        float co, float si) {
  const bool c = (__popc(l & RL) & 1) != 0;
  const float cc = c ? co : 1.f, ss = c ? si : 0.f;
#pragma unroll
  for (int q = 0; q < 4; ++q) {
    const float rx = CR[q].x, ry = CR[q].y, ix = CI[q].x, iy = CI[q].y;
    CR[q] = (v2f){cc * rx + ss * iy, cc * ry + ss * ix};
    CI[q] = (v2f){cc * ix - ss * ry, cc * iy - ss * rx};
  }
}

// U3 on a lane bit (packed).
template <int RL, int VL>
__device__ __forceinline__ void u3_lane(v2f (&CR)[4], v2f (&CI)[4], int l,
                                        const G1& g) {
  const bool hi = (__popc(l & RL) & 1) != 0;
  const float Ar = hi ? g.r11 : g.r00, Aii = hi ? g.i11 : g.i00;
  const float Br = hi ? g.r10 : g.r01, Bi = hi ? g.i10 : g.i01;
  const v2f cAr = dup(Ar), cAi = dup(Aii), cAiN = dup(-Aii);
  const v2f cBr = dup(Br), cBi = dup(Bi), cBiN = dup(-Bi);
  v2f PR[4], PI[4];
#pragma unroll
  for (int q = 0; q < 4; ++q) { PR[q] = shf2<VL>(CR[q]); PI[q] = shf2<VL>(CI[q]); }
#pragma unroll
  for (int q = 0; q < 4; ++q)
    cplx_fma(CR[q], CI[q], PR[q], PI[q], cAr, cAi, cAiN, cBr, cBi, cBiN);
}

// U3 on pack axis (scalar within-pair).
__device__ __forceinline__ void u3_reg4(v2f (&CR)[4], v2f (&CI)[4], const G1& g) {
#pragma unroll
  for (int q = 0; q < 4; ++q) {
    const float lr = CR[q].x, li = CI[q].x, hr = CR[q].y, hj = CI[q].y;
    CR[q] = (v2f){g.r00 * lr - g.i00 * li + g.r01 * hr - g.i01 * hj,
                  g.r10 * lr - g.i10 * li + g.r11 * hr - g.i11 * hj};
    CI[q] = (v2f){g.r00 * li + g.i00 * lr + g.r01 * hj + g.i01 * hr,
                  g.r10 * li + g.i10 * lr + g.r11 * hj + g.i11 * hr};
  }
}

__device__ __forceinline__ G1 u3_gate(const float* __restrict__ u3p, int k) {
  float st, ct, sp, cp, sl, cl;
  __sincosf(0.5f * u3p[3 * k], &st, &ct);
  __sincosf(u3p[3 * k + 1], &sp, &cp);
  __sincosf(u3p[3 * k + 2], &sl, &cl);
  G1 g;
  g.r00 = ct;        g.i00 = 0.f;
  g.r01 = -cl * st;  g.i01 = -sl * st;
  g.r10 = cp * st;   g.i10 = sp * st;
  g.r11 = (cp * cl - sp * sl) * ct;
  g.i11 = (sp * cl + cp * sl) * ct;
  return g;
}

__global__ __launch_bounds__(256, 4) void qcnn_kernel(
    const float* __restrict__ theta, const float* __restrict__ phi,
    const float* __restrict__ crx, const float* __restrict__ u3p,
    float* __restrict__ out, int nbatch) {
  const int tid = blockIdx.x * blockDim.x + threadIdx.x;
  const int wave = tid >> 6;
  const int lane = threadIdx.x & 63;
  const int l = lane & 31;
  int b = wave * 2 + (lane >> 5);
  if (b >= nbatch) b = nbatch - 1;

  v2f CR[4], CI[4];
#pragma unroll
  for (int q = 0; q < 4; ++q) { CR[q] = dup(0.f); CI[q] = dup(0.f); }
  if (l == 0) CR[0].x = 1.f;

  const float th = theta[b], ph = phi[b];
  float sth, cth, sph, cph;
  __sincosf(0.5f * th, &sth, &cth);
  __sincosf(0.5f * ph, &sph, &cph);
  const float uAr = cph * cth, uBi = sph * sth;
  const float uAip = sph * cth, uBrp = cph * sth;

#define ULANE(RL, VL) u_lane<RL, VL>(CR, CI, l, uAr, uBi, uAip, uBrp)
#define UPAIR(a, b_) apply_pair(CR[a], CI[a], CR[b_], CI[b_], uAr, -uAip, \
                                -uBrp, uBi, uBrp, uBi, uAr, uAip)
#define UREGS() do { u_reg4(CR, CI, uAr, uBi, uAip, uBrp); \
                     UPAIR(0, 2); UPAIR(1, 3); \
                     UPAIR(0, 1); UPAIR(2, 3); } while (0)
#define RING(RL45, VL70) do { cnot_lr4<RL45>(CR, CI, l); \
                              cnot_swap42(CR, CI); cnot_swap21(CR, CI); \
                              cnot_rl<VL70>(CR, CI); } while (0)

  // cycle 1
  ULANE(16, 16); ULANE(8, 8);   ULANE(4, 4);   ULANE(2, 2);  ULANE(1, 1);
  UREGS(); RING(31, 24);
  // cycle 2
  ULANE(16, 24); ULANE(24, 12); ULANE(28, 6);  ULANE(30, 3); ULANE(31, 1);
  UREGS(); RING(21, 20);
  // cycle 3
  ULANE(16, 20); ULANE(8, 10);  ULANE(20, 5);  ULANE(10, 2); ULANE(21, 1);
  UREGS(); RING(19, 30);
  // cycle 4
  ULANE(16, 30); ULANE(24, 15); ULANE(12, 7);  ULANE(6, 3);  ULANE(19, 1);
  UREGS(); RING(17, 17);
#undef RING
#undef UREGS
#undef UPAIR
#undef ULANE

  // ---- QCNN section (lane maps: w0(16,17) w1(8,8) w2(4,4) w3(2,2) w4(17,1);
  // reg wires 5,6,7 = bits 2,1,0; pack axis = bit2) ----
  float co, si;
#define LD(k) __sincosf(0.5f * crx[k], &si, &co)
  LD(0); crx_ll<16, 8>(CR, CI, l, co, si);   // (0,1)
  LD(1); crx_ll<4, 2>(CR, CI, l, co, si);    // (2,3)
  LD(2); crx_lr4<17>(CR, CI, l, co, si);     // (4,5) pack-target
  LD(3);                                     // (6,7): ctrl bit1, tgt bit0
  crx_pairv(CR[2], CI[2], CR[3], CI[3], dup(co), dup(si), dup(-si));
  LD(4); crx_ll<8, 4>(CR, CI, l, co, si);    // (1,2)
  LD(5); crx_ll<2, 1>(CR, CI, l, co, si);    // (3,4)
  LD(6);                                     // (5,6): ctrl pack -> half coeffs
  {
    const v2f cCC = (v2f){1.f, co}, cSS = (v2f){0.f, si}, cSSN = (v2f){0.f, -si};
    crx_pairv(CR[0], CI[0], CR[2], CI[2], cCC, cSS, cSSN);
    crx_pairv(CR[1], CI[1], CR[3], CI[3], cCC, cSS, cSSN);
  }

  { G1 g = u3_gate(u3p, 0); u3_lane<8, 8>(CR, CI, l, g); }  // wire 1
  { G1 g = u3_gate(u3p, 1); u3_lane<2, 2>(CR, CI, l, g); }  // wire 3
  { G1 g = u3_gate(u3p, 2); u3_reg4(CR, CI, g); }           // wire 5 pack
  { G1 g = u3_gate(u3p, 3);                                 // wire 7 (bit0)
    apply_pair(CR[0], CI[0], CR[1], CI[1], g.r00, g.i00, g.r01, g.i01,
               g.r10, g.i10, g.r11, g.i11);
    apply_pair(CR[2], CI[2], CR[3], CI[3], g.r00, g.i00, g.r01, g.i01,
               g.r10, g.i10, g.r11, g.i11); }

  LD(7); crx_ll<8, 2>(CR, CI, l, co, si);    // (1,3)
  LD(8);                                     // (5,7): ctrl pack, tgt bit0
  {
    const v2f cCC = (v2f){1.f, co}, cSS = (v2f){0.f, si}, cSSN = (v2f){0.f, -si};
    crx_pairv(CR[0], CI[0], CR[1], CI[1], cCC, cSS, cSSN);
    crx_pairv(CR[2], CI[2], CR[3], CI[3], cCC, cSS, cSSN);
  }
  LD(9); crx_lr4<2>(CR, CI, l, co, si);      // (3,5) pack-target

  { G1 g = u3_gate(u3p, 4); u3_lane<2, 2>(CR, CI, l, g); }  // wire 3
  { G1 g = u3_gate(u3p, 5);                                 // wire 7
    apply_pair(CR[0], CI[0], CR[1], CI[1], g.r00, g.i00, g.r01, g.i01,
               g.r10, g.i10, g.r11, g.i11);
    apply_pair(CR[2], CI[2], CR[3], CI[3], g.r00, g.i00, g.r01, g.i01,
               g.r10, g.i10, g.r11, g.i11); }

  LD(10);                                    // (3,7): lane ctrl R=2, tgt bit0
  {
    const bool c = (__popc(l & 2) & 1) != 0;
    const float cc = c ? co : 1.f, ss = c ? si : 0.f;
    const v2f cCC = dup(cc), cSS = dup(ss), cSSN = dup(-ss);
    crx_pairv(CR[0], CI[0], CR[1], CI[1], cCC, cSS, cSSN);
    crx_pairv(CR[2], CI[2], CR[3], CI[3], cCC, cSS, cSSN);
  }

  { G1 g = u3_gate(u3p, 6);                                 // wire 7
    apply_pair(CR[0], CI[0], CR[1], CI[1], g.r00, g.i00, g.r01, g.i01,
               g.r10, g.i10, g.r11, g.i11);
    apply_pair(CR[2], CI[2], CR[3], CI[3], g.r00, g.i00, g.r01, g.i01,
               g.r10, g.i10, g.r11, g.i11); }
#undef LD

  // <Z_wire7>: sign = reg bit0 = q&1 (both halves of each pack share sign).
  v2f S0 = pkfma(CI[0], CI[0], pkmul(CR[0], CR[0]));
  v2f S1 = pkfma(CI[1], CI[1], pkmul(CR[1], CR[1]));
  v2f S2 = pkfma(CI[2], CI[2], pkmul(CR[2], CR[2]));
  v2f S3 = pkfma(CI[3], CI[3], pkmul(CR[3], CR[3]));
  const v2f T = (S0 + S2) - (S1 + S3);
  float v = T.x + T.y;
  v += shxm<1>(v); v += shxm<2>(v); v += shxm<4>(v);
  v += shxm<8>(v); v += shxm<16>(v);
  if (l == 0) out[b] = fmaxf(v, 0.f);
}

extern "C" void kernel_launch(void* const* d_in, const int* in_sizes, int n_in,
                              void* d_out, int out_size, void* d_ws, size_t ws_size,
                              hipStream_t stream) {
  const float* theta = (const float*)d_in[0];
  const float* phi = (const float*)d_in[1];
  const float* crx = (const float*)d_in[2];
  const float* u3p = (const float*)d_in[3];
  float* out = (float*)d_out;
  const int nb = in_sizes[0];
  const int elems_per_block = 8;  // 4 waves * 2 elements
  dim3 block(256);
  dim3 grid((nb + elems_per_block - 1) / elems_per_block);
  qcnn_kernel<<<grid, block, 0, stream>>>(theta, phi, crx, u3p, out, nb);
}

// Round 6
// 78.176 us; speedup vs baseline: 1.2588x; 1.0138x over previous
//
#include <hip/hip_runtime.h>
#include <math.h>

// Layout (unchanged from r5): 8 complex amps/lane, 2 batch elements/wave64
// (one per 32-lane half).  Amp index p = l<<3 | r, l = lane&31 (5 lane bits),
// r = reg (3 bits).  Regs packed as float2 along reg bit2 (wire 5).
//
// Round 6 changes:
//  1. prep_kernel precomputes the batch-invariant CRX (co,si) pairs and U3
//     gate matrices into d_ws; main waves read them (wave-uniform loads)
//     instead of re-running ~29 sincosf + gate-build per wave.
//  2. pack-axis gates (u_reg4 / u3_reg4 / crx_lr4) now use VOP3P op_sel to
//     broadcast/swap source halves -> packed, half the slots of scalar.
//  3. non-DPP cross-lane moves use ds_swizzle directly (no bpermute addr).
//
// Lane-bit lazy GF(2) CNOT relabeling (validated r4/r5):
//  C1 U:(16,16)(8,8)(4,4)(2,2)(1,1)      lr-ctrl 31  rl-V 24
//  C2 U:(16,24)(24,12)(28,6)(30,3)(31,1) lr-ctrl 21  rl-V 20
//  C3 U:(16,20)(8,10)(20,5)(10,2)(21,1)  lr-ctrl 19  rl-V 30
//  C4 U:(16,30)(24,15)(12,7)(6,3)(19,1)  lr-ctrl 17  rl-V 17
//  QCNN: w0(16,17) w1(8,8) w2(4,4) w3(2,2) w4(17,1); reg wires 5,6,7=bits 2,1,0.

typedef float v2f __attribute__((ext_vector_type(2)));

__device__ __forceinline__ v2f pkmul(v2f a, v2f b) {
  v2f d; asm("v_pk_mul_f32 %0, %1, %2" : "=v"(d) : "v"(a), "v"(b)); return d;
}
__device__ __forceinline__ v2f pkfma(v2f a, v2f b, v2f c) {
  v2f d; asm("v_pk_fma_f32 %0, %1, %2, %3" : "=v"(d) : "v"(a), "v"(b), "v"(c)); return d;
}
// src1 broadcast LOW half to both results: d.x=a.x*b.x(+c.x), d.y=a.y*b.x(+c.y)
__device__ __forceinline__ v2f pkmul_lo1(v2f a, v2f b) {
  v2f d; asm("v_pk_mul_f32 %0, %1, %2 op_sel:[0,0] op_sel_hi:[1,0]"
             : "=v"(d) : "v"(a), "v"(b)); return d;
}
__device__ __forceinline__ v2f pkfma_lo1(v2f a, v2f b, v2f c) {
  v2f d; asm("v_pk_fma_f32 %0, %1, %2, %3 op_sel:[0,0,0] op_sel_hi:[1,0,1]"
             : "=v"(d) : "v"(a), "v"(b), "v"(c)); return d;
}
// src1 broadcast HIGH half to both results
__device__ __forceinline__ v2f pkfma_hi1(v2f a, v2f b, v2f c) {
  v2f d; asm("v_pk_fma_f32 %0, %1, %2, %3 op_sel:[0,1,0] op_sel_hi:[1,1,1]"
             : "=v"(d) : "v"(a), "v"(b), "v"(c)); return d;
}
// src1 halves SWAPPED: d.x uses b.y, d.y uses b.x
__device__ __forceinline__ v2f pkfma_sw1(v2f a, v2f b, v2f c) {
  v2f d; asm("v_pk_fma_f32 %0, %1, %2, %3 op_sel:[0,1,0] op_sel_hi:[1,0,1]"
             : "=v"(d) : "v"(a), "v"(b), "v"(c)); return d;
}
__device__ __forceinline__ v2f dup(float x) { return (v2f){x, x}; }

template <int M>
__device__ __forceinline__ float shxm(float v) {
  if constexpr (M == 1 || M == 2 || M == 3 || M == 7 || M == 8 || M == 15) {
    constexpr int ctrl = (M == 1) ? 0xB1 : (M == 2) ? 0x4E : (M == 3) ? 0x1B
                         : (M == 7) ? 0x141 : (M == 8) ? 0x128 : 0x140;
    return __int_as_float(__builtin_amdgcn_update_dpp(
        0, __float_as_int(v), ctrl, 0xF, 0xF, true));
  } else {
    // all masks in this layout are < 32: single ds_swizzle (BitMode xor)
    return __int_as_float(__builtin_amdgcn_ds_swizzle(
        __float_as_int(v), (M << 10) | 0x1F));
  }
}
template <int M>
__device__ __forceinline__ v2f shf2(v2f a) {
  return (v2f){shxm<M>(a.x), shxm<M>(a.y)};
}

struct G1 { float r00, i00, r01, i01, r10, i10, r11, i11; };

__device__ __forceinline__ void cplx_fma(v2f& R, v2f& I, v2f PR, v2f PI,
                                         v2f cAr, v2f cAi, v2f cAiN,
                                         v2f cBr, v2f cBi, v2f cBiN) {
  v2f NR = pkfma(cBiN, PI, pkfma(cBr, PR, pkfma(cAiN, I, pkmul(cAr, R))));
  v2f NI = pkfma(cBi, PR, pkfma(cBr, PI, pkfma(cAi, R, pkmul(cAr, I))));
  R = NR; I = NI;
}

// general 2x2 complex gate on a reg pair (lo,hi) across two packs.
__device__ __forceinline__ void apply_pair(v2f& LR, v2f& LI, v2f& HR, v2f& HI,
                                           float g00r, float g00i, float g01r,
                                           float g01i, float g10r, float g10i,
                                           float g11r, float g11i) {
  const v2f a00r = dup(g00r), a00i = dup(g00i), n00i = dup(-g00i);
  const v2f a01r = dup(g01r), a01i = dup(g01i), n01i = dup(-g01i);
  const v2f a10r = dup(g10r), a10i = dup(g10i), n10i = dup(-g10i);
  const v2f a11r = dup(g11r), a11i = dup(g11i), n11i = dup(-g11i);
  v2f NLR = pkfma(n01i, HI, pkfma(a01r, HR, pkfma(n00i, LI, pkmul(a00r, LR))));
  v2f NLI = pkfma(a01i, HR, pkfma(a01r, HI, pkfma(a00i, LR, pkmul(a00r, LI))));
  v2f NHR = pkfma(n11i, HI, pkfma(a11r, HR, pkfma(n10i, LI, pkmul(a10r, LR))));
  v2f NHI = pkfma(a11i, HR, pkfma(a11r, HI, pkfma(a10i, LR, pkmul(a10r, LI))));
  LR = NLR; LI = NLI; HR = NHR; HI = NHI;
}

__device__ __forceinline__ void crx_pairv(v2f& LR, v2f& LI, v2f& HR, v2f& HI,
                                          v2f cCC, v2f cSS, v2f cSSN) {
  v2f NLR = pkfma(cSS, HI, pkmul(cCC, LR));
  v2f NLI = pkfma(cSSN, HR, pkmul(cCC, LI));
  v2f NHR = pkfma(cSS, LI, pkmul(cCC, HR));
  v2f NHI = pkfma(cSSN, LR, pkmul(cCC, HI));
  LR = NLR; LI = NLI; HR = NHR; HI = NHI;
}

// U = RZ@RY on a lane bit (fully packed).
template <int RL, int VL>
__device__ __forceinline__ void u_lane(v2f (&CR)[4], v2f (&CI)[4], int l,
                                       float uAr, float uBi, float uAip,
                                       float uBrp) {
  const bool hi = (__popc(l & RL) & 1) != 0;
  const float Ai = hi ? uAip : -uAip;
  const float Br = hi ? uBrp : -uBrp;
  const v2f cAr = dup(uAr), cAi = dup(Ai), cAiN = dup(-Ai);
  const v2f cBr = dup(Br), cBi = dup(uBi), cBiN = dup(-uBi);
  v2f PR[4], PI[4];
#pragma unroll
  for (int q = 0; q < 4; ++q) { PR[q] = shf2<VL>(CR[q]); PI[q] = shf2<VL>(CI[q]); }
#pragma unroll
  for (int q = 0; q < 4; ++q)
    cplx_fma(CR[q], CI[q], PR[q], PI[q], cAr, cAi, cAiN, cBr, cBi, cBiN);
}

// generic 2x2 gate on the PACK axis via op_sel (8 pk per pack).
// g00=(a,b) acts on lo, g01=(c,d) couples hi->lo, g10, g11 analogous.
__device__ __forceinline__ void gate_pack(v2f (&CR)[4], v2f (&CI)[4],
                                          v2f cA, v2f cB, v2f cBn,
                                          v2f cC, v2f cD, v2f cDn) {
#pragma unroll
  for (int q = 0; q < 4; ++q) {
    v2f NR = pkfma_hi1(cDn, CI[q], pkfma_hi1(cC, CR[q],
             pkfma_lo1(cBn, CI[q], pkmul_lo1(cA, CR[q]))));
    v2f NI = pkfma_hi1(cD, CR[q], pkfma_hi1(cC, CI[q],
             pkfma_lo1(cB, CR[q], pkmul_lo1(cA, CI[q]))));
    CR[q] = NR; CI[q] = NI;
  }
}

// U on pack axis: coefficient vectors from U matrix
__device__ __forceinline__ void u_reg4(v2f (&CR)[4], v2f (&CI)[4], float uAr,
                                       float uBi, float uAip, float uBrp) {
  gate_pack(CR, CI,
            (v2f){uAr, uBrp},    // (g00r, g10r)
            (v2f){-uAip, uBi},   // (g00i, g10i)
            (v2f){uAip, -uBi},   // negated
            (v2f){-uBrp, uAr},   // (g01r, g11r)
            (v2f){uBi, uAip},    // (g01i, g11i)
            (v2f){-uBi, -uAip});
}

__device__ __forceinline__ void u3_reg4(v2f (&CR)[4], v2f (&CI)[4], const G1& g) {
  gate_pack(CR, CI,
            (v2f){g.r00, g.r10},
            (v2f){g.i00, g.i10},
            (v2f){-g.i00, -g.i10},
            (v2f){g.r01, g.r11},
            (v2f){g.i01, g.i11},
            (v2f){-g.i01, -g.i11});
}

// ring CNOT (4,5): lane ctrl -> conditional .x/.y swap.
template <int RL>
__device__ __forceinline__ void cnot_lr4(v2f (&CR)[4], v2f (&CI)[4], int l) {
  const bool c = (__popc(l & RL) & 1) != 0;
#pragma unroll
  for (int q = 0; q < 4; ++q) {
    const float ax = CR[q].x, ay = CR[q].y;
    CR[q] = (v2f){c ? ay : ax, c ? ax : ay};
    const float bx = CI[q].x, by = CI[q].y;
    CI[q] = (v2f){c ? by : bx, c ? bx : by};
  }
}

__device__ __forceinline__ void cnot_swap42(v2f (&CR)[4], v2f (&CI)[4]) {
  float t;
  t = CR[0].y; CR[0].y = CR[2].y; CR[2].y = t;
  t = CR[1].y; CR[1].y = CR[3].y; CR[3].y = t;
  t = CI[0].y; CI[0].y = CI[2].y; CI[2].y = t;
  t = CI[1].y; CI[1].y = CI[3].y; CI[3].y = t;
}

__device__ __forceinline__ void cnot_swap21(v2f (&CR)[4], v2f (&CI)[4]) {
  v2f t;
  t = CR[2]; CR[2] = CR[3]; CR[3] = t;
  t = CI[2]; CI[2] = CI[3]; CI[3] = t;
}

template <int VL>
__device__ __forceinline__ void cnot_rl(v2f (&CR)[4], v2f (&CI)[4]) {
  CR[1] = shf2<VL>(CR[1]); CI[1] = shf2<VL>(CI[1]);
  CR[3] = shf2<VL>(CR[3]); CI[3] = shf2<VL>(CI[3]);
}

template <int RL, int VL>
__device__ __forceinline__ void crx_ll(v2f (&CR)[4], v2f (&CI)[4], int l,
                                       float co, float si) {
  const bool c = (__popc(l & RL) & 1) != 0;
  const float cc = c ? co : 1.f, ss = c ? si : 0.f;
  const v2f cCC = dup(cc), cSS = dup(ss), cSSN = dup(-ss);
  v2f PR[4], PI[4];
#pragma unroll
  for (int q = 0; q < 4; ++q) { PR[q] = shf2<VL>(CR[q]); PI[q] = shf2<VL>(CI[q]); }
#pragma unroll
  for (int q = 0; q < 4; ++q) {
    CR[q] = pkfma(cSS, PI[q], pkmul(cCC, CR[q]));
    CI[q] = pkfma(cSSN, PR[q], pkmul(cCC, CI[q]));
  }
}

// CRX lane ctrl -> target pack axis, via op_sel swap (4 pk per pack).
template <int RL>
__device__ __forceinline__ void crx_lr4(v2f (&CR)[4], v2f (&CI)[4], int l,
                                        float co, float si) {
  const bool c = (__popc(l & RL) & 1) != 0;
  const float cc = c ? co : 1.f, ss = c ? si : 0.f;
  const v2f cc2 = dup(cc), ss2 = dup(ss), ssN2 = dup(-ss);
#pragma unroll
  for (int q = 0; q < 4; ++q) {
    v2f NR = pkfma_sw1(ss2, CI[q], pkmul(cc2, CR[q]));
    v2f NI = pkfma_sw1(ssN2, CR[q], pkmul(cc2, CI[q]));
    CR[q] = NR; CI[q] = NI;
  }
}

// U3 on a lane bit (packed), gate from precomputed table.
template <int RL, int VL>
__device__ __forceinline__ void u3_lane(v2f (&CR)[4], v2f (&CI)[4], int l,
                                        const G1& g) {
  const bool hi = (__popc(l & RL) & 1) != 0;
  const float Ar = hi ? g.r11 : g.r00, Aii = hi ? g.i11 : g.i00;
  const float Br = hi ? g.r10 : g.r01, Bi = hi ? g.i10 : g.i01;
  const v2f cAr = dup(Ar), cAi = dup(Aii), cAiN = dup(-Aii);
  const v2f cBr = dup(Br), cBi = dup(Bi), cBiN = dup(-Bi);
  v2f PR[4], PI[4];
#pragma unroll
  for (int q = 0; q < 4; ++q) { PR[q] = shf2<VL>(CR[q]); PI[q] = shf2<VL>(CI[q]); }
#pragma unroll
  for (int q = 0; q < 4; ++q)
    cplx_fma(CR[q], CI[q], PR[q], PI[q], cAr, cAi, cAiN, cBr, cBi, cBiN);
}

__device__ __forceinline__ G1 load_g1(const float* __restrict__ cs, int k) {
  const float* p = cs + 22 + 8 * k;
  G1 g;
  g.r00 = p[0]; g.i00 = p[1]; g.r01 = p[2]; g.i01 = p[3];
  g.r10 = p[4]; g.i10 = p[5]; g.r11 = p[6]; g.i11 = p[7];
  return g;
}

// ---- prep: batch-invariant coefficients -> d_ws ----
// ws[0..21]: (co,si) for crx[0..10];  ws[22+8k .. 29+8k]: G1 for u3 gate k.
__global__ void prep_kernel(const float* __restrict__ crx,
                            const float* __restrict__ u3p,
                            float* __restrict__ ws) {
  const int t = threadIdx.x;
  if (t < 11) {
    float s, c;
    sincosf(0.5f * crx[t], &s, &c);
    ws[2 * t] = c; ws[2 * t + 1] = s;
  } else if (t >= 16 && t < 23) {
    const int k = t - 16;
    float st, ct, sp, cp, sl, cl;
    sincosf(0.5f * u3p[3 * k], &st, &ct);
    sincosf(u3p[3 * k + 1], &sp, &cp);
    sincosf(u3p[3 * k + 2], &sl, &cl);
    float* o = ws + 22 + 8 * k;
    o[0] = ct;            o[1] = 0.f;
    o[2] = -cl * st;      o[3] = -sl * st;
    o[4] = cp * st;       o[5] = sp * st;
    o[6] = (cp * cl - sp * sl) * ct;
    o[7] = (sp * cl + cp * sl) * ct;
  }
}

__global__ __launch_bounds__(256, 4) void qcnn_kernel(
    const float* __restrict__ theta, const float* __restrict__ phi,
    const float* __restrict__ cs, float* __restrict__ out, int nbatch) {
  const int tid = blockIdx.x * blockDim.x + threadIdx.x;
  const int wave = tid >> 6;
  const int lane = threadIdx.x & 63;
  const int l = lane & 31;
  int b = wave * 2 + (lane >> 5);
  if (b >= nbatch) b = nbatch - 1;

  v2f CR[4], CI[4];
#pragma unroll
  for (int q = 0; q < 4; ++q) { CR[q] = dup(0.f); CI[q] = dup(0.f); }
  if (l == 0) CR[0].x = 1.f;

  const float th = theta[b], ph = phi[b];
  float sth, cth, sph, cph;
  __sincosf(0.5f * th, &sth, &cth);
  __sincosf(0.5f * ph, &sph, &cph);
  const float uAr = cph * cth, uBi = sph * sth;
  const float uAip = sph * cth, uBrp = cph * sth;

#define ULANE(RL, VL) u_lane<RL, VL>(CR, CI, l, uAr, uBi, uAip, uBrp)
#define UPAIR(a, b_) apply_pair(CR[a], CI[a], CR[b_], CI[b_], uAr, -uAip, \
                                -uBrp, uBi, uBrp, uBi, uAr, uAip)
#define UREGS() do { u_reg4(CR, CI, uAr, uBi, uAip, uBrp); \
                     UPAIR(0, 2); UPAIR(1, 3); \
                     UPAIR(0, 1); UPAIR(2, 3); } while (0)
#define RING(RL45, VL70) do { cnot_lr4<RL45>(CR, CI, l); \
                              cnot_swap42(CR, CI); cnot_swap21(CR, CI); \
                              cnot_rl<VL70>(CR, CI); } while (0)

  // cycle 1
  ULANE(16, 16); ULANE(8, 8);   ULANE(4, 4);   ULANE(2, 2);  ULANE(1, 1);
  UREGS(); RING(31, 24);
  // cycle 2
  ULANE(16, 24); ULANE(24, 12); ULANE(28, 6);  ULANE(30, 3); ULANE(31, 1);
  UREGS(); RING(21, 20);
  // cycle 3
  ULANE(16, 20); ULANE(8, 10);  ULANE(20, 5);  ULANE(10, 2); ULANE(21, 1);
  UREGS(); RING(19, 30);
  // cycle 4
  ULANE(16, 30); ULANE(24, 15); ULANE(12, 7);  ULANE(6, 3);  ULANE(19, 1);
  UREGS(); RING(17, 17);
#undef RING
#undef UREGS
#undef UPAIR
#undef ULANE

  // ---- QCNN section ----
#define LD(k) const float co##k = cs[2 * k], si##k = cs[2 * k + 1]
  LD(0); crx_ll<16, 8>(CR, CI, l, co0, si0);   // (0,1)
  LD(1); crx_ll<4, 2>(CR, CI, l, co1, si1);    // (2,3)
  LD(2); crx_lr4<17>(CR, CI, l, co2, si2);     // (4,5) pack-target
  LD(3);                                       // (6,7): ctrl bit1, tgt bit0
  crx_pairv(CR[2], CI[2], CR[3], CI[3], dup(co3), dup(si3), dup(-si3));
  LD(4); crx_ll<8, 4>(CR, CI, l, co4, si4);    // (1,2)
  LD(5); crx_ll<2, 1>(CR, CI, l, co5, si5);    // (3,4)
  LD(6);                                       // (5,6): ctrl pack -> half coeffs
  {
    const v2f cCC = (v2f){1.f, co6}, cSS = (v2f){0.f, si6}, cSSN = (v2f){0.f, -si6};
    crx_pairv(CR[0], CI[0], CR[2], CI[2], cCC, cSS, cSSN);
    crx_pairv(CR[1], CI[1], CR[3], CI[3], cCC, cSS, cSSN);
  }

  { G1 g = load_g1(cs, 0); u3_lane<8, 8>(CR, CI, l, g); }  // wire 1
  { G1 g = load_g1(cs, 1); u3_lane<2, 2>(CR, CI, l, g); }  // wire 3
  { G1 g = load_g1(cs, 2); u3_reg4(CR, CI, g); }           // wire 5 pack
  { G1 g = load_g1(cs, 3);                                 // wire 7 (bit0)
    apply_pair(CR[0], CI[0], CR[1], CI[1], g.r00, g.i00, g.r01, g.i01,
               g.r10, g.i10, g.r11, g.i11);
    apply_pair(CR[2], CI[2], CR[3], CI[3], g.r00, g.i00, g.r01, g.i01,
               g.r10, g.i10, g.r11, g.i11); }

  LD(7); crx_ll<8, 2>(CR, CI, l, co7, si7);    // (1,3)
  LD(8);                                       // (5,7): ctrl pack, tgt bit0
  {
    const v2f cCC = (v2f){1.f, co8}, cSS = (v2f){0.f, si8}, cSSN = (v2f){0.f, -si8};
    crx_pairv(CR[0], CI[0], CR[1], CI[1], cCC, cSS, cSSN);
    crx_pairv(CR[2], CI[2], CR[3], CI[3], cCC, cSS, cSSN);
  }
  LD(9); crx_lr4<2>(CR, CI, l, co9, si9);      // (3,5) pack-target

  { G1 g = load_g1(cs, 4); u3_lane<2, 2>(CR, CI, l, g); }  // wire 3
  { G1 g = load_g1(cs, 5);                                 // wire 7
    apply_pair(CR[0], CI[0], CR[1], CI[1], g.r00, g.i00, g.r01, g.i01,
               g.r10, g.i10, g.r11, g.i11);
    apply_pair(CR[2], CI[2], CR[3], CI[3], g.r00, g.i00, g.r01, g.i01,
               g.r10, g.i10, g.r11, g.i11); }

  LD(10);                                      // (3,7): lane ctrl R=2, tgt bit0
  {
    const bool c = (__popc(l & 2) & 1) != 0;
    const float cc = c ? co10 : 1.f, ss = c ? si10 : 0.f;
    const v2f cCC = dup(cc), cSS = dup(ss), cSSN = dup(-ss);
    crx_pairv(CR[0], CI[0], CR[1], CI[1], cCC, cSS, cSSN);
    crx_pairv(CR[2], CI[2], CR[3], CI[3], cCC, cSS, cSSN);
  }

  { G1 g = load_g1(cs, 6);                                 // wire 7
    apply_pair(CR[0], CI[0], CR[1], CI[1], g.r00, g.i00, g.r01, g.i01,
               g.r10, g.i10, g.r11, g.i11);
    apply_pair(CR[2], CI[2], CR[3], CI[3], g.r00, g.i00, g.r01, g.i01,
               g.r10, g.i10, g.r11, g.i11); }
#undef LD

  // <Z_wire7>: sign = reg bit0 = q&1.
  v2f S0 = pkfma(CI[0], CI[0], pkmul(CR[0], CR[0]));
  v2f S1 = pkfma(CI[1], CI[1], pkmul(CR[1], CR[1]));
  v2f S2 = pkfma(CI[2], CI[2], pkmul(CR[2], CR[2]));
  v2f S3 = pkfma(CI[3], CI[3], pkmul(CR[3], CR[3]));
  const v2f T = (S0 + S2) - (S1 + S3);
  float v = T.x + T.y;
  v += shxm<1>(v); v += shxm<2>(v); v += shxm<4>(v);
  v += shxm<8>(v); v += shxm<16>(v);
  if (l == 0) out[b] = fmaxf(v, 0.f);
}

extern "C" void kernel_launch(void* const* d_in, const int* in_sizes, int n_in,
                              void* d_out, int out_size, void* d_ws, size_t ws_size,
                              hipStream_t stream) {
  const float* theta = (const float*)d_in[0];
  const float* phi = (const float*)d_in[1];
  const float* crx = (const float*)d_in[2];
  const float* u3p = (const float*)d_in[3];
  float* out = (float*)d_out;
  float* ws = (float*)d_ws;
  const int nb = in_sizes[0];

  prep_kernel<<<1, 64, 0, stream>>>(crx, u3p, ws);

  const int elems_per_block = 8;  // 4 waves * 2 elements
  dim3 block(256);
  dim3 grid((nb + elems_per_block - 1) / elems_per_block);
  qcnn_kernel<<<grid, block, 0, stream>>>(theta, phi, ws, out, nb);
}